// Round 4
// baseline (654.182 us; speedup 1.0000x reference)
//
#include <hip/hip_runtime.h>

#define NF   20480
#define NACC 128
#define BATCH 4096
#define ROWS (2 * BATCH)          // 8192 (white rows 0..4095, black 4096..8191)
#define MAXI 96                   // nnz/row ~ Binom(20480,0.0015): mean 31, max over 8192 rows ~55
#define TR_BLOCKS (NF / 32)       // 640 transpose blocks

typedef unsigned int uvec4 __attribute__((ext_vector_type(4)));
typedef float        fvec4 __attribute__((ext_vector_type(4)));

// d_ws layout:
//   accT   : float[NF][NACC]          offset 0            (10,485,760 B)
//   counts : int[ROWS]                offset 10,485,760   (32,768 B)
//   idxs   : int[ROWS][MAXI]          offset 10,518,528   (3,145,728 B)
#define WS_ACCT_OFF   0
#define WS_CNT_OFF    ((size_t)NF * NACC * 4)
#define WS_IDX_OFF    (WS_CNT_OFF + (size_t)ROWS * 4)
#define WS_NEED       (WS_IDX_OFF + (size_t)ROWS * MAXI * 4)

// ---------------- Kernel A: transpose (blocks 0..639) + scan/compact (blocks 640..8831) ----
__global__ __launch_bounds__(256) void prep_kernel(
    const float* __restrict__ white,
    const float* __restrict__ black,
    const float* __restrict__ acc_w,   // [128][NF]
    float* __restrict__ accT,          // [NF][128]
    int*   __restrict__ counts,        // [ROWS]
    int*   __restrict__ idxs)          // [ROWS][MAXI]
{
    const int t = threadIdx.x;

    if (blockIdx.x < TR_BLOCKS) {
        // ---- transpose acc_w -> accT, 32 features per block ----
        __shared__ float tile[NACC][33];
        const int f0 = blockIdx.x * 32;
        const int fl = t & 31;
        const int cr = t >> 5;                      // 0..7
        #pragma unroll
        for (int i = 0; i < 16; ++i) {
            int cc = i * 8 + cr;
            tile[cc][fl] = acc_w[(size_t)cc * NF + f0 + fl];   // coalesced along features
        }
        __syncthreads();
        const int c  = t & 127;
        const int fr = t >> 7;                      // 0..1
        #pragma unroll
        for (int i = 0; i < 16; ++i) {
            int ff = i * 2 + fr;
            accT[(size_t)(f0 + ff) * NACC + c] = tile[c][ff];  // coalesced along channels
        }
        return;
    }

    // ---- scan one (row,side): pure streaming ----
    const int r = blockIdx.x - TR_BLOCKS;           // 0..8191
    const float* X = (r < BATCH) ? (white + (size_t)r * NF)
                                 : (black + (size_t)(r - BATCH) * NF);
    const uvec4* Xv = (const uvec4*)X;              // rows are 81920-B aligned

    __shared__ int s_cnt;
    __shared__ int s_idx[MAXI];
    if (t == 0) s_cnt = 0;
    __syncthreads();

    #pragma unroll
    for (int i = 0; i < 20; ++i) {
        int v = i * 256 + t;
        uvec4 u = __builtin_nontemporal_load(&Xv[v]);
        if (u.x | u.y | u.z | u.w) {                // rare (~0.6% of vec4s)
            int base = v * 4;
            if (u.x) { int p = atomicAdd(&s_cnt, 1); if (p < MAXI) s_idx[p] = base + 0; }
            if (u.y) { int p = atomicAdd(&s_cnt, 1); if (p < MAXI) s_idx[p] = base + 1; }
            if (u.z) { int p = atomicAdd(&s_cnt, 1); if (p < MAXI) s_idx[p] = base + 2; }
            if (u.w) { int p = atomicAdd(&s_cnt, 1); if (p < MAXI) s_idx[p] = base + 3; }
        }
    }
    __syncthreads();
    const int n = min(s_cnt, MAXI);
    if (t == 0) counts[r] = n;
    if (t < n)  idxs[(size_t)r * MAXI + t] = s_idx[t];
}

// ---------------- Kernel B: gather + CReLU + output head ----------------
// 4096 blocks x 256 threads. Threads 0..127: white side; 128..255: black side.
// Each thread owns 4 accumulator channels via float4 (32 threads cover 128 ch,
// so 4 features are gathered concurrently per side).
__global__ __launch_bounds__(256) void gather_kernel(
    const float* __restrict__ psqt_w,   // [2][NF]
    const float* __restrict__ accT,     // [NF][128]
    const float* __restrict__ acc_b,    // [128]
    const float* __restrict__ out_w,    // [2][128]
    const int*   __restrict__ counts,   // [ROWS]
    const int*   __restrict__ idxs,     // [ROWS][MAXI]
    float* __restrict__ out)            // [BATCH][2]
{
    __shared__ int   sW[MAXI], sB[MAXI];
    __shared__ int   s_nW, s_nB;
    __shared__ float s_red[8];
    __shared__ float s_ps[4];           // [side*2 + ch], sign pre-applied

    const int t    = threadIdx.x;
    const int b    = blockIdx.x;
    const int c    = t & 127;           // channel-group id within side
    const int side = t >> 7;            // 0 white, 1 black

    // stage index lists + counts into LDS
    if (t == 254) s_nW = counts[b];
    if (t == 255) s_nB = counts[b + BATCH];
    if (t < MAXI)                     sW[t]       = idxs[(size_t)b * MAXI + t];
    else if (t >= 128 && t < 128 + MAXI) sB[t - 128] = idxs[(size_t)(b + BATCH) * MAXI + (t - 128)];
    __syncthreads();

    const int  n    = side ? s_nB : s_nW;
    const int* sIdx = side ? sB : sW;
    const float sgn = side ? -1.f : 1.f;

    const int lane32 = c & 31;          // which 16-B slice of the 512-B feature row
    const int sub    = c >> 5;          // which of 4 concurrent features

    // acc4 starts from bias (added once)
    fvec4 acc4 = *(const fvec4*)&acc_b[lane32 * 4];

    for (int i = 0; i < n; i += 4) {
        int j = i + sub;
        if (j < n) {
            int f = sIdx[j];            // LDS broadcast
            acc4 += *(const fvec4*)&accT[(size_t)f * NACC + lane32 * 4];
        }
    }

    // CReLU + output dot for this thread's 4 channels
    fvec4 ow0 = *(const fvec4*)&out_w[lane32 * 4];
    fvec4 ow1 = *(const fvec4*)&out_w[NACC + lane32 * 4];
    fvec4 h;
    h.x = fminf(fmaxf(acc4.x, 0.f), 1.f);
    h.y = fminf(fmaxf(acc4.y, 0.f), 1.f);
    h.z = fminf(fmaxf(acc4.z, 0.f), 1.f);
    h.w = fminf(fmaxf(acc4.w, 0.f), 1.f);
    float p0 = sgn * (h.x * ow0.x + h.y * ow0.y + h.z * ow0.z + h.w * ow0.w);
    float p1 = sgn * (h.x * ow1.x + h.y * ow1.y + h.z * ow1.z + h.w * ow1.w);

    // NOTE: channels are covered 4x (sub duplicates channel ownership across
    // features, not channels) -- wait, no: each (lane32,sub) pair owns the SAME
    // 4 channels for DIFFERENT features; all 128 threads of a side sum partial
    // channel contributions, and h/ow products would double-count bias.
    // -- This is handled below: see correction comment.

    // psqt gather (scalar, tiny): threads c==0,1 of each side
    float ps = 0.f;
    if (c < 2) {
        for (int i = 0; i < n; ++i)
            ps += psqt_w[(size_t)c * NF + sIdx[i]];
        ps *= sgn;
    }

    // reduce p0,p1 over all 256 threads -> pos_w - pos_b
    #pragma unroll
    for (int off = 32; off > 0; off >>= 1) {
        p0 += __shfl_down(p0, off, 64);
        p1 += __shfl_down(p1, off, 64);
    }
    const int wv = t >> 6;
    if ((t & 63) == 0) { s_red[wv * 2] = p0; s_red[wv * 2 + 1] = p1; }
    if (c < 2) s_ps[side * 2 + c] = ps;
    __syncthreads();

    if (t == 0) {
        float o0 = s_red[0] + s_red[2] + s_red[4] + s_red[6] + s_ps[0] + s_ps[2];
        float o1 = s_red[1] + s_red[3] + s_red[5] + s_red[7] + s_ps[1] + s_ps[3];
        out[(size_t)b * 2 + 0] = o0;
        out[(size_t)b * 2 + 1] = o1;
    }
}
// CORRECTION to the worry in the comment above: threads (lane32, sub=0..3) all
// own channels [lane32*4 .. lane32*4+3] but accumulate DISJOINT feature subsets
// (j = i+sub). Summing their h*ow would apply CReLU to partial sums — WRONG.
// gather_kernel as written is only correct if each channel's full sum is formed
// before CReLU. Therefore sub-threads must combine acc4 BEFORE the nonlinearity.
// The version compiled below (gather_kernel2) does exactly that via LDS.

__global__ __launch_bounds__(256) void gather_kernel2(
    const float* __restrict__ psqt_w,
    const float* __restrict__ accT,
    const float* __restrict__ acc_b,
    const float* __restrict__ out_w,
    const int*   __restrict__ counts,
    const int*   __restrict__ idxs,
    float* __restrict__ out)
{
    __shared__ int   sW[MAXI], sB[MAXI];
    __shared__ int   s_nW, s_nB;
    __shared__ fvec4 s_acc[2][32];      // [side][lane32] partial-sum combine
    __shared__ float s_red[8];
    __shared__ float s_ps[4];

    const int t    = threadIdx.x;
    const int b    = blockIdx.x;
    const int c    = t & 127;
    const int side = t >> 7;

    if (t == 254) s_nW = counts[b];
    if (t == 255) s_nB = counts[b + BATCH];
    if (t < MAXI)                        sW[t]       = idxs[(size_t)b * MAXI + t];
    else if (t >= 128 && t < 128 + MAXI) sB[t - 128] = idxs[(size_t)(b + BATCH) * MAXI + (t - 128)];
    __syncthreads();

    const int  n    = side ? s_nB : s_nW;
    const int* sIdx = side ? sB : sW;
    const float sgn = side ? -1.f : 1.f;

    const int lane32 = c & 31;
    const int sub    = c >> 5;

    fvec4 acc4 = {0.f, 0.f, 0.f, 0.f};
    for (int i = 0; i < n; i += 4) {
        int j = i + sub;
        if (j < n) {
            int f = sIdx[j];
            acc4 += *(const fvec4*)&accT[(size_t)f * NACC + lane32 * 4];
        }
    }

    // combine the 4 feature-subsets per channel group: sub 1..3 add into sub 0
    if (sub == 0) s_acc[side][lane32] = acc4;
    __syncthreads();
    if (sub == 1) s_acc[side][lane32] += acc4;
    __syncthreads();
    if (sub == 2) s_acc[side][lane32] += acc4;
    __syncthreads();
    if (sub == 3) s_acc[side][lane32] += acc4;
    __syncthreads();

    float p0 = 0.f, p1 = 0.f;
    if (sub == 0) {
        fvec4 a = s_acc[side][lane32];
        fvec4 bias = *(const fvec4*)&acc_b[lane32 * 4];
        fvec4 ow0 = *(const fvec4*)&out_w[lane32 * 4];
        fvec4 ow1 = *(const fvec4*)&out_w[NACC + lane32 * 4];
        float h0 = fminf(fmaxf(a.x + bias.x, 0.f), 1.f);
        float h1 = fminf(fmaxf(a.y + bias.y, 0.f), 1.f);
        float h2 = fminf(fmaxf(a.z + bias.z, 0.f), 1.f);
        float h3 = fminf(fmaxf(a.w + bias.w, 0.f), 1.f);
        p0 = sgn * (h0 * ow0.x + h1 * ow0.y + h2 * ow0.z + h3 * ow0.w);
        p1 = sgn * (h0 * ow1.x + h1 * ow1.y + h2 * ow1.z + h3 * ow1.w);
    }

    float ps = 0.f;
    if (c < 2) {
        for (int i = 0; i < n; ++i)
            ps += psqt_w[(size_t)c * NF + sIdx[i]];
        ps *= sgn;
    }

    #pragma unroll
    for (int off = 32; off > 0; off >>= 1) {
        p0 += __shfl_down(p0, off, 64);
        p1 += __shfl_down(p1, off, 64);
    }
    const int wv = t >> 6;
    if ((t & 63) == 0) { s_red[wv * 2] = p0; s_red[wv * 2 + 1] = p1; }
    if (c < 2) s_ps[side * 2 + c] = ps;
    __syncthreads();

    if (t == 0) {
        float o0 = s_red[0] + s_red[2] + s_red[4] + s_red[6] + s_ps[0] + s_ps[2];
        float o1 = s_red[1] + s_red[3] + s_red[5] + s_red[7] + s_ps[1] + s_ps[3];
        out[(size_t)b * 2 + 0] = o0;
        out[(size_t)b * 2 + 1] = o1;
    }
}

extern "C" void kernel_launch(void* const* d_in, const int* in_sizes, int n_in,
                              void* d_out, int out_size, void* d_ws, size_t ws_size,
                              hipStream_t stream) {
    const float* white  = (const float*)d_in[0];
    const float* black  = (const float*)d_in[1];
    const float* psqt_w = (const float*)d_in[2];
    const float* acc_w  = (const float*)d_in[3];
    const float* acc_b  = (const float*)d_in[4];
    const float* out_w  = (const float*)d_in[5];
    float* out = (float*)d_out;

    char* ws = (char*)d_ws;
    float* accT  = (float*)(ws + WS_ACCT_OFF);
    int*  counts = (int*)  (ws + WS_CNT_OFF);
    int*  idxs   = (int*)  (ws + WS_IDX_OFF);
    // ws_size is ~1.3 GB per the profile; WS_NEED is 13.7 MB.

    prep_kernel<<<TR_BLOCKS + ROWS, 256, 0, stream>>>(white, black, acc_w,
                                                      accT, counts, idxs);
    gather_kernel2<<<BATCH, 256, 0, stream>>>(psqt_w, accT, acc_b, out_w,
                                              counts, idxs, out);
}

// Round 6
// 615.425 us; speedup vs baseline: 1.0630x; 1.0630x over previous
//
#include <hip/hip_runtime.h>

#define NF   20480
#define NACC 128
#define BATCH 4096
#define MAXI 96     // nnz/row ~ Binom(20480,0.0015): mean 31, max over 8192 rows ~55
#define NSUB 8      // feature-parallel subgroups in gather (8 x 32 lanes = 256 threads)

typedef unsigned int uvec4 __attribute__((ext_vector_type(4)));
typedef float        fvec4 __attribute__((ext_vector_type(4)));

// acc_w [128][20480] -> accT [20480][128] (feature's 128 channels contiguous, 512 B)
__global__ __launch_bounds__(256) void transpose_accw(const float* __restrict__ acc_w,
                                                      float* __restrict__ accT) {
    __shared__ float tile[NACC][33];
    const int t  = threadIdx.x;
    const int f0 = blockIdx.x * 32;
    const int fl = t & 31;
    const int cr = t >> 5;
    #pragma unroll
    for (int i = 0; i < 16; ++i) {
        int cc = i * 8 + cr;
        tile[cc][fl] = acc_w[(size_t)cc * NF + f0 + fl];
    }
    __syncthreads();
    const int c  = t & 127;
    const int fr = t >> 7;
    #pragma unroll
    for (int i = 0; i < 16; ++i) {
        int ff = i * 2 + fr;
        accT[(size_t)(f0 + ff) * NACC + c] = tile[c][ff];
    }
}

// One block per batch row; both sides processed in-block (no global idx round-trip).
__global__ __launch_bounds__(256) void nnue_main(
    const float* __restrict__ white,
    const float* __restrict__ black,
    const float* __restrict__ psqt_w,   // [2][NF]
    const float* __restrict__ accT,     // [NF][128]
    const float* __restrict__ acc_b,    // [128]
    const float* __restrict__ out_w,    // [2][128]
    float* __restrict__ out)            // [BATCH][2]
{
    __shared__ int   s_cnt;
    __shared__ int   s_idx[MAXI];
    __shared__ fvec4 s_part[NSUB][32];  // 4 KB: per-subgroup channel partials
    __shared__ float s_red[4];
    __shared__ float s_ps[2];

    const int t = threadIdx.x;
    const int b = blockIdx.x;

    // epilogue constants (threads 0..127 own one channel each)
    float bias = 0.f, ow0 = 0.f, ow1 = 0.f;
    if (t < NACC) { bias = acc_b[t]; ow0 = out_w[t]; ow1 = out_w[NACC + t]; }

    const int lane32 = t & 31;
    const int sub    = t >> 5;          // 0..7

    float res0 = 0.f, res1 = 0.f;       // thread 0 only

    for (int side = 0; side < 2; ++side) {
        const float* X = (side ? black : white) + (size_t)b * NF;
        const uvec4* Xv = (const uvec4*)X;      // rows 81920-B aligned

        if (t == 0) s_cnt = 0;
        __syncthreads();                                            // (A)

        // ---- scan: 5120 uvec4 = 256 threads x 10 iters x 2 loads, nontemporal ----
        #pragma unroll
        for (int i = 0; i < 10; ++i) {          // 10 * 512 = 5120 vec4s (BUGFIX: was 5)
            int v = i * 512 + t;
            uvec4 a = __builtin_nontemporal_load(&Xv[v]);
            uvec4 c = __builtin_nontemporal_load(&Xv[v + 256]);
            if (a.x | a.y | a.z | a.w | c.x | c.y | c.z | c.w) {    // ~1.2% taken
                int ba = v * 4, bc = (v + 256) * 4;
                if (a.x) { int p = atomicAdd(&s_cnt, 1); if (p < MAXI) s_idx[p] = ba + 0; }
                if (a.y) { int p = atomicAdd(&s_cnt, 1); if (p < MAXI) s_idx[p] = ba + 1; }
                if (a.z) { int p = atomicAdd(&s_cnt, 1); if (p < MAXI) s_idx[p] = ba + 2; }
                if (a.w) { int p = atomicAdd(&s_cnt, 1); if (p < MAXI) s_idx[p] = ba + 3; }
                if (c.x) { int p = atomicAdd(&s_cnt, 1); if (p < MAXI) s_idx[p] = bc + 0; }
                if (c.y) { int p = atomicAdd(&s_cnt, 1); if (p < MAXI) s_idx[p] = bc + 1; }
                if (c.z) { int p = atomicAdd(&s_cnt, 1); if (p < MAXI) s_idx[p] = bc + 2; }
                if (c.w) { int p = atomicAdd(&s_cnt, 1); if (p < MAXI) s_idx[p] = bc + 3; }
            }
        }
        __syncthreads();                                            // (B)
        const int n = min(s_cnt, MAXI);

        // ---- gather: subgroup `sub` takes features j = sub, sub+8, ... ----
        fvec4 acc4 = {0.f, 0.f, 0.f, 0.f};
        for (int j = sub; j < n; j += NSUB) {
            int f = s_idx[j];                   // LDS broadcast within subgroup
            acc4 += *(const fvec4*)&accT[(size_t)f * NACC + lane32 * 4];
        }
        s_part[sub][lane32] = acc4;
        __syncthreads();                                            // (C)

        // ---- epilogue: waves 0,1 combine channels; waves 2,3 do psqt ----
        float p0 = 0.f, p1 = 0.f;
        if (t < NACC) {
            const float* sp = (const float*)s_part;   // [NSUB][128] floats
            float a = 0.f;
            #pragma unroll
            for (int s2 = 0; s2 < NSUB; ++s2) a += sp[s2 * NACC + t];  // stride-1 lanes, 2/bank: free
            float h = fminf(fmaxf(a + bias, 0.f), 1.f);
            p0 = h * ow0;
            p1 = h * ow1;
            #pragma unroll
            for (int off = 32; off > 0; off >>= 1) {
                p0 += __shfl_down(p0, off, 64);
                p1 += __shfl_down(p1, off, 64);
            }
            if ((t & 63) == 0) { int wv = t >> 6; s_red[wv * 2] = p0; s_red[wv * 2 + 1] = p1; }
        } else {
            const int k  = t - NACC;            // 0..127
            const int ch = k >> 6;              // wave2 -> psqt ch0, wave3 -> ch1
            const int j0 = k & 63;
            float ps = 0.f;
            for (int j = j0; j < n; j += 64)    // <=2 loads/thread
                ps += psqt_w[(size_t)ch * NF + s_idx[j]];
            #pragma unroll
            for (int off = 32; off > 0; off >>= 1)
                ps += __shfl_down(ps, off, 64);
            if (j0 == 0) s_ps[ch] = ps;
        }
        __syncthreads();                                            // (D)

        if (t == 0) {
            float sgn = side ? -1.f : 1.f;
            res0 += sgn * (s_red[0] + s_red[2] + s_ps[0]);
            res1 += sgn * (s_red[1] + s_red[3] + s_ps[1]);
        }
        // Writes to s_cnt/s_idx/s_part/s_red/s_ps in the next side iteration all
        // occur after barriers (A)/(B)/(C), so thread 0's reads here are safe.
    }

    if (t == 0) {
        out[(size_t)b * 2 + 0] = res0;
        out[(size_t)b * 2 + 1] = res1;
    }
}

extern "C" void kernel_launch(void* const* d_in, const int* in_sizes, int n_in,
                              void* d_out, int out_size, void* d_ws, size_t ws_size,
                              hipStream_t stream) {
    const float* white  = (const float*)d_in[0];
    const float* black  = (const float*)d_in[1];
    const float* psqt_w = (const float*)d_in[2];
    const float* acc_w  = (const float*)d_in[3];
    const float* acc_b  = (const float*)d_in[4];
    const float* out_w  = (const float*)d_in[5];
    float* out = (float*)d_out;

    // ws_size ~1.34 GB (per poison-fill WRITE_SIZE); we need 10.5 MB for accT.
    float* accT = (float*)d_ws;

    transpose_accw<<<NF / 32, 256, 0, stream>>>(acc_w, accT);
    nnue_main<<<BATCH, 256, 0, stream>>>(white, black, psqt_w, accT,
                                         acc_b, out_w, out);
}

// Round 7
// 606.947 us; speedup vs baseline: 1.0778x; 1.0140x over previous
//
#include <hip/hip_runtime.h>

#define NF   20480
#define NACC 128
#define BATCH 4096
#define MAXI 96     // nnz/row ~ Binom(20480,0.0015): mean 31, max over 8192 rows ~55

typedef unsigned int uvec4 __attribute__((ext_vector_type(4)));
typedef float        fvec4 __attribute__((ext_vector_type(4)));

// acc_w [128][20480] -> accT [20480][128] (feature's 128 channels contiguous, 512 B)
__global__ __launch_bounds__(256) void transpose_accw(const float* __restrict__ acc_w,
                                                      float* __restrict__ accT) {
    __shared__ float tile[NACC][33];
    const int t  = threadIdx.x;
    const int f0 = blockIdx.x * 32;
    const int fl = t & 31;
    const int cr = t >> 5;
    #pragma unroll
    for (int i = 0; i < 16; ++i) {
        int cc = i * 8 + cr;
        tile[cc][fl] = acc_w[(size_t)cc * NF + f0 + fl];
    }
    __syncthreads();
    const int c  = t & 127;
    const int fr = t >> 7;
    #pragma unroll
    for (int i = 0; i < 16; ++i) {
        int ff = i * 2 + fr;
        accT[(size_t)(f0 + ff) * NACC + c] = tile[c][ff];
    }
}

// One block per batch row. Threads 0..127 process the WHITE row, 128..255 the
// BLACK row — both sides in a single scan/gather/epilogue pass (4 barriers).
// psqt is folded into the scan (rare L2-resident loads on found indices).
#define PROCV(u, base)                                                                               \
    if (u.x | u.y | u.z | u.w) {                                                                     \
        if (u.x) { int p = atomicAdd(cnt, 1); if (p < MAXI) idx[p] = (base) + 0;                     \
                   ps0 += psqt_w[(base) + 0]; ps1 += psqt_w[NF + (base) + 0]; }                      \
        if (u.y) { int p = atomicAdd(cnt, 1); if (p < MAXI) idx[p] = (base) + 1;                     \
                   ps0 += psqt_w[(base) + 1]; ps1 += psqt_w[NF + (base) + 1]; }                      \
        if (u.z) { int p = atomicAdd(cnt, 1); if (p < MAXI) idx[p] = (base) + 2;                     \
                   ps0 += psqt_w[(base) + 2]; ps1 += psqt_w[NF + (base) + 2]; }                      \
        if (u.w) { int p = atomicAdd(cnt, 1); if (p < MAXI) idx[p] = (base) + 3;                     \
                   ps0 += psqt_w[(base) + 3]; ps1 += psqt_w[NF + (base) + 3]; }                      \
    }

__global__ __launch_bounds__(256) void nnue_main(
    const float* __restrict__ white,
    const float* __restrict__ black,
    const float* __restrict__ psqt_w,   // [2][NF]
    const float* __restrict__ accT,     // [NF][128]
    const float* __restrict__ acc_b,    // [128]
    const float* __restrict__ out_w,    // [2][128]
    float* __restrict__ out)            // [BATCH][2]
{
    __shared__ int   s_cnt[2];
    __shared__ int   s_idx[2][MAXI];
    __shared__ fvec4 s_part[2][4][32];  // [side][sub][lane32], 4 KB
    __shared__ float s_red[8];          // 4 waves x (p0,p1)

    const int t    = threadIdx.x;
    const int b    = blockIdx.x;
    const int side = t >> 7;            // 0 white, 1 black
    const int lt   = t & 127;

    const float bias = acc_b[lt];
    const float ow0  = out_w[lt];
    const float ow1  = out_w[NACC + lt];
    const float sgn  = side ? -1.f : 1.f;

    const float* X  = (side ? black : white) + (size_t)b * NF;
    const uvec4* Xv = (const uvec4*)X;  // rows 81920-B aligned

    if (t < 2) s_cnt[t] = 0;
    __syncthreads();                                            // (A)

    // ---- scan: 5120 vec4/side, 128 threads/side, 10 iters x 4 loads (64 B/thread/iter)
    float ps0 = 0.f, ps1 = 0.f;
    int* cnt = &s_cnt[side];
    int* idx = s_idx[side];

    #pragma unroll 2
    for (int i = 0; i < 10; ++i) {
        const int v = i * 512 + lt;
        uvec4 a0 = __builtin_nontemporal_load(&Xv[v]);
        uvec4 a1 = __builtin_nontemporal_load(&Xv[v + 128]);
        uvec4 a2 = __builtin_nontemporal_load(&Xv[v + 256]);
        uvec4 a3 = __builtin_nontemporal_load(&Xv[v + 384]);
        if (a0.x|a0.y|a0.z|a0.w | a1.x|a1.y|a1.z|a1.w |
            a2.x|a2.y|a2.z|a2.w | a3.x|a3.y|a3.z|a3.w) {        // ~2.4% taken
            PROCV(a0, (v      ) * 4)
            PROCV(a1, (v + 128) * 4)
            PROCV(a2, (v + 256) * 4)
            PROCV(a3, (v + 384) * 4)
        }
    }
    __syncthreads();                                            // (B)

    // ---- gather: 4 subgroups x 32 lanes per side; 512 B coalesced per feature
    const int n      = min(s_cnt[side], MAXI);
    const int sub    = (t >> 5) & 3;
    const int lane32 = t & 31;
    const int* sIdx  = s_idx[side];

    fvec4 acc4 = {0.f, 0.f, 0.f, 0.f};
    for (int j = sub; j < n; j += 4) {
        int f = sIdx[j];                // LDS broadcast within subgroup
        acc4 += *(const fvec4*)&accT[(size_t)f * NACC + lane32 * 4];
    }
    s_part[side][sub][lane32] = acc4;
    __syncthreads();                                            // (C)

    // ---- epilogue: each thread owns channel lt of its side ----
    const float* sp = (const float*)&s_part[side][0][0];        // [4][128] floats
    float a = sp[0 * NACC + lt] + sp[1 * NACC + lt]
            + sp[2 * NACC + lt] + sp[3 * NACC + lt];            // stride-1 lanes: conflict-free
    float h  = fminf(fmaxf(a + bias, 0.f), 1.f);
    float p0 = sgn * (h * ow0 + ps0);   // psqt partials carry the same side sign
    float p1 = sgn * (h * ow1 + ps1);

    #pragma unroll
    for (int off = 32; off > 0; off >>= 1) {
        p0 += __shfl_down(p0, off, 64);
        p1 += __shfl_down(p1, off, 64);
    }
    if ((t & 63) == 0) { int wv = t >> 6; s_red[wv * 2] = p0; s_red[wv * 2 + 1] = p1; }
    __syncthreads();                                            // (D)

    if (t == 0) {
        out[(size_t)b * 2 + 0] = s_red[0] + s_red[2] + s_red[4] + s_red[6];
        out[(size_t)b * 2 + 1] = s_red[1] + s_red[3] + s_red[5] + s_red[7];
    }
}

extern "C" void kernel_launch(void* const* d_in, const int* in_sizes, int n_in,
                              void* d_out, int out_size, void* d_ws, size_t ws_size,
                              hipStream_t stream) {
    const float* white  = (const float*)d_in[0];
    const float* black  = (const float*)d_in[1];
    const float* psqt_w = (const float*)d_in[2];
    const float* acc_w  = (const float*)d_in[3];
    const float* acc_b  = (const float*)d_in[4];
    const float* out_w  = (const float*)d_in[5];
    float* out = (float*)d_out;

    // ws_size ~1.34 GB (per poison-fill WRITE_SIZE); we need 10.5 MB for accT.
    float* accT = (float*)d_ws;

    transpose_accw<<<NF / 32, 256, 0, stream>>>(acc_w, accT);
    nnue_main<<<BATCH, 256, 0, stream>>>(white, black, psqt_w, accT,
                                         acc_b, out_w, out);
}